// Round 3
// baseline (8533.184 us; speedup 1.0000x reference)
//
#include <hip/hip_runtime.h>
#include <cstdint>
#include <cstddef>

// Problem constants (from reference): B=64, E=512, H=512, V=32000, T=32
#define BB 64
#define EE 512
#define HH 512
#define VV 32000
#define TT 32

#define NLOGB 500      // k_logits grid (VV/64)
#define PSTRIDE 512    // partials row stride

// ---------------------------------------------------------------------------
// k_gates: fused {argmax-reduce -> token, embed gather, LSTM gates GEMM, cell}.
//   grid = 256 blocks: jt = blockIdx>>3 (32 tiles of 16 j), bt = blockIdx&7
//   (8 tiles of 8 b).
//   Prologue: this block's 8 tokens. step==0: caps[b]. Else: reduce the 500
//   per-block argmax partials from last step's k_logits (32 lanes per b,
//   coalesced, first-index tie-break == jnp.argmax).
//   Staging: x = embW[tok[b]] and h (8 rows x 512 f, stride 516 so the 8
//   b-broadcast read streams start on different banks) into LDS.
//   Main: thread (j_l 0..15, kh 0..1, b_l 0..7) computes 4 gate dots of
//   length 512 (kh=0: x.Wih_row, kh=1: h.Whh_row); shfl_xor(8) pairs halves.
//   Each W element is read once per block-row => 64 MB/step L2 traffic.
//   Epilogue (kh==0 lanes): biases + sigmoid/tanh cell, write h (b-major),
//   hT (k-major for k_logits' broadcast reads), c.
// ---------------------------------------------------------------------------
#define XPAD 516   // 516 mod 32 = 4 -> b-rows start 4 banks apart

__global__ __launch_bounds__(256) void k_gates(
    const float* __restrict__ embW, const float* __restrict__ Wih,
    const float* __restrict__ Whh, const float* __restrict__ bih,
    const float* __restrict__ bhh, const float* __restrict__ hin,
    float* __restrict__ hout, const float* __restrict__ cin,
    float* __restrict__ cout, float* __restrict__ hT,
    const int* __restrict__ caps,
    const float* __restrict__ pval, const int* __restrict__ pidx,
    int step)
{
    __shared__ float xs[8 * XPAD];
    __shared__ float hs[8 * XPAD];
    __shared__ int   tok_s[8];

    const int jt = blockIdx.x >> 3;      // 0..31
    const int bt = blockIdx.x & 7;       // 0..7
    const int t  = threadIdx.x;

    // ---- tokens for this block's 8 b's ----
    if (step == 0) {
        if (t < 8) tok_s[t] = caps[bt * 8 + t];
    } else {
        const int b_l2 = t >> 5;         // 0..7
        const int part = t & 31;         // 32 lanes per b (stays in half-wave)
        const int b2   = bt * 8 + b_l2;
        float best = -3.4e38f; int bi = 0x7fffffff;
        #pragma unroll 4
        for (int i = part; i < NLOGB; i += 32) {
            float v = pval[b2 * PSTRIDE + i];
            int  ix = pidx[b2 * PSTRIDE + i];
            if (v > best || (v == best && ix < bi)) { best = v; bi = ix; }
        }
        #pragma unroll
        for (int off = 1; off < 32; off <<= 1) {
            float ov = __shfl_xor(best, off);
            int   oi = __shfl_xor(bi, off);
            if (ov > best || (ov == best && oi < bi)) { best = ov; bi = oi; }
        }
        if (part == 0) tok_s[b_l2] = bi;
    }
    __syncthreads();

    // ---- stage x and h: 8 rows x 512 floats each; 32 threads per row ----
    {
        const int rr = t >> 5;           // 0..7  (b_local)
        const int cc = t & 31;
        const int b  = bt * 8 + rr;
        const int tk = tok_s[rr];
        const float4* xrow = (const float4*)(embW + (size_t)tk * EE);
        const float4* hrow = (const float4*)(hin + (size_t)b * HH);
        float4* xd = (float4*)(xs + rr * XPAD);   // rr*516*4 B = 16B-aligned
        float4* hd = (float4*)(hs + rr * XPAD);
        #pragma unroll
        for (int i = 0; i < 4; ++i) {
            xd[cc + i * 32] = xrow[cc + i * 32];
            hd[cc + i * 32] = hrow[cc + i * 32];
        }
    }
    __syncthreads();

    const int b_l = t & 7;               // 0..7
    const int kh  = (t >> 3) & 1;        // 0: x/Wih half, 1: h/Whh half
    const int j_l = t >> 4;              // 0..15
    const int j   = jt * 16 + j_l;
    const int b   = bt * 8 + b_l;

    const float*  Wsrc = kh ? Whh : Wih;
    const float4* vsrc = (const float4*)((kh ? hs : xs) + b_l * XPAD);

    float g4[4];
    #pragma unroll
    for (int g = 0; g < 4; ++g) {
        const float4* wr = (const float4*)(Wsrc + (size_t)(g * HH + j) * EE);
        float s = 0.f;
        #pragma unroll 8
        for (int q = 0; q < 128; ++q) {
            float4 w = wr[q];
            float4 v = vsrc[q];
            s = fmaf(w.x, v.x, s); s = fmaf(w.y, v.y, s);
            s = fmaf(w.z, v.z, s); s = fmaf(w.w, v.w, s);
        }
        g4[g] = s;
    }
    #pragma unroll
    for (int g = 0; g < 4; ++g) g4[g] += __shfl_xor(g4[g], 8);

    if (kh == 0) {
        float gi = g4[0] + bih[j]          + bhh[j];
        float gf = g4[1] + bih[HH + j]     + bhh[HH + j];
        float gg = g4[2] + bih[2*HH + j]   + bhh[2*HH + j];
        float go = g4[3] + bih[3*HH + j]   + bhh[3*HH + j];
        float si = 1.f / (1.f + expf(-gi));
        float sf = 1.f / (1.f + expf(-gf));
        float sg = tanhf(gg);
        float so = 1.f / (1.f + expf(-go));
        const int ci = b * HH + j;
        float cn = sf * cin[ci] + si * sg;
        float hn = so * tanhf(cn);
        cout[ci] = cn;
        hout[ci] = hn;
        hT[(size_t)j * BB + b] = hn;
    }
}

// ---------------------------------------------------------------------------
// k_logits: out[b][n] = h[b] . lin_W[n] + lin_b[n]   for all 64 b, one column
// per lane. grid = 500 blocks x 256 thr. Thread = (col 0..63, kh 0..3), k-range
// 128 each; 64 fp32 accumulators/lane; lin_W streamed per-lane (read once
// per step), h broadcast via wave-uniform float4 reads of hT[k][b].
// Epilogue: LDS 4-way k-reduce, bias, coalesced d_out writes, per-block
// argmax partials (first-index tie-break, matching jnp.argmax).
// ---------------------------------------------------------------------------
__global__ __launch_bounds__(256) void k_logits(
    const float* __restrict__ linW, const float* __restrict__ linb,
    const float* __restrict__ hT, float* __restrict__ dout,
    float* __restrict__ pval, int* __restrict__ pidx, int step)
{
    const int col = threadIdx.x & 63;
    const int kh  = threadIdx.x >> 6;        // 0..3, one wave each
    const int n   = blockIdx.x * 64 + col;

    const float4* wrow = (const float4*)(linW + (size_t)n * HH + kh * 128);
    const float*  hk   = hT + (size_t)kh * 128 * BB;

    float acc[BB];
    #pragma unroll
    for (int b = 0; b < BB; ++b) acc[b] = 0.f;

    for (int q = 0; q < 32; ++q) {           // 32 float4 chunks of 128 k's
        float4 w = wrow[q];
        const float4* h0 = (const float4*)(hk + ((size_t)q * 4 + 0) * BB);
        const float4* h1 = (const float4*)(hk + ((size_t)q * 4 + 1) * BB);
        const float4* h2 = (const float4*)(hk + ((size_t)q * 4 + 2) * BB);
        const float4* h3 = (const float4*)(hk + ((size_t)q * 4 + 3) * BB);
        #pragma unroll
        for (int b4 = 0; b4 < 16; ++b4) {
            float4 hv;
            hv = h0[b4];
            acc[b4*4+0] = fmaf(w.x, hv.x, acc[b4*4+0]);
            acc[b4*4+1] = fmaf(w.x, hv.y, acc[b4*4+1]);
            acc[b4*4+2] = fmaf(w.x, hv.z, acc[b4*4+2]);
            acc[b4*4+3] = fmaf(w.x, hv.w, acc[b4*4+3]);
            hv = h1[b4];
            acc[b4*4+0] = fmaf(w.y, hv.x, acc[b4*4+0]);
            acc[b4*4+1] = fmaf(w.y, hv.y, acc[b4*4+1]);
            acc[b4*4+2] = fmaf(w.y, hv.z, acc[b4*4+2]);
            acc[b4*4+3] = fmaf(w.y, hv.w, acc[b4*4+3]);
            hv = h2[b4];
            acc[b4*4+0] = fmaf(w.z, hv.x, acc[b4*4+0]);
            acc[b4*4+1] = fmaf(w.z, hv.y, acc[b4*4+1]);
            acc[b4*4+2] = fmaf(w.z, hv.z, acc[b4*4+2]);
            acc[b4*4+3] = fmaf(w.z, hv.w, acc[b4*4+3]);
            hv = h3[b4];
            acc[b4*4+0] = fmaf(w.w, hv.x, acc[b4*4+0]);
            acc[b4*4+1] = fmaf(w.w, hv.y, acc[b4*4+1]);
            acc[b4*4+2] = fmaf(w.w, hv.z, acc[b4*4+2]);
            acc[b4*4+3] = fmaf(w.w, hv.w, acc[b4*4+3]);
        }
    }

    // 4-way k reduction into kh==0, chunked (16 b's per round, 12 KiB LDS)
    __shared__ float red[3][64][16];
    for (int r = 0; r < 4; ++r) {
        if (kh > 0) {
            #pragma unroll
            for (int i = 0; i < 16; ++i) red[kh - 1][col][i] = acc[r * 16 + i];
        }
        __syncthreads();
        if (kh == 0) {
            #pragma unroll
            for (int i = 0; i < 16; ++i)
                acc[r * 16 + i] += red[0][col][i] + red[1][col][i] + red[2][col][i];
        }
        __syncthreads();
    }

    if (kh == 0) {                            // wave 0, 64 lanes = 64 cols
        const float bias = linb[n];
        for (int b = 0; b < BB; ++b) {
            float v = acc[b] + bias;
            dout[((size_t)(b * TT + step)) * VV + n] = v;
            float mv = v; int mi = n;
            #pragma unroll
            for (int off = 32; off > 0; off >>= 1) {
                float ov = __shfl_xor(mv, off);
                int   oi = __shfl_xor(mi, off);
                if (ov > mv || (ov == mv && oi < mi)) { mv = ov; mi = oi; }
            }
            if (col == 0) {
                pval[b * PSTRIDE + blockIdx.x] = mv;
                pidx[b * PSTRIDE + blockIdx.x] = mi;
            }
        }
    }
}

// ---------------------------------------------------------------------------
extern "C" void kernel_launch(void* const* d_in, const int* in_sizes, int n_in,
                              void* d_out, int out_size, void* d_ws, size_t ws_size,
                              hipStream_t stream)
{
    const float* feat = (const float*)d_in[0];   // (B,H)
    const int*   caps = (const int*)d_in[1];     // (B,1) int32
    // d_in[2] = lengths (=32), unused
    const float* embW = (const float*)d_in[3];   // (V,E)
    const float* Wih  = (const float*)d_in[4];   // (4H,E)
    const float* Whh  = (const float*)d_in[5];   // (4H,H)
    const float* bih  = (const float*)d_in[6];   // (4H,)
    const float* bhh  = (const float*)d_in[7];   // (4H,)
    const float* linW = (const float*)d_in[8];   // (V,H)
    const float* linb = (const float*)d_in[9];   // (V,)
    float* dout = (float*)d_out;                 // (B,T,V) f32

    // workspace layout (~0.9 MiB)
    float* ws_f = (float*)d_ws;
    float* ha   = ws_f;                      // 32768 f
    float* hb   = ha + BB * HH;              // 32768 f
    float* cb   = hb + BB * HH;              // 32768 f
    float* hT   = cb + BB * HH;              // 32768 f
    float* pval = hT + BB * HH;              // 64*512 f
    int*   pidx = (int*)(pval + BB * PSTRIDE);   // 64*512 i
    // no separate init kernel: step 0 reads feat (h,c) and caps (tok) directly

    for (int t = 0; t < TT; ++t) {
        const float* hin = (t == 0) ? feat : ((t & 1) ? ha : hb);
        float*      hout = (t & 1) ? hb : ha;
        const float* ci  = (t == 0) ? feat : cb;
        k_gates<<<256, 256, 0, stream>>>(embW, Wih, Whh, bih, bhh,
                                         hin, hout, ci, cb, hT,
                                         caps, pval, pidx, t);
        k_logits<<<NLOGB, 256, 0, stream>>>(linW, linb, hT, dout,
                                            pval, pidx, t);
    }
}

// Round 4
// 2918.901 us; speedup vs baseline: 2.9234x; 2.9234x over previous
//
#include <hip/hip_runtime.h>
#include <cstdint>
#include <cstddef>

// Problem constants (from reference): B=64, E=512, H=512, V=32000, T=32
#define BB 64
#define EE 512
#define HH 512
#define VV 32000
#define TT 32

#define NLOGB 500      // k_logits grid (VV/64)
#define PSTRIDE 512    // partials row stride
#define XPAD 516       // LDS row stride: 516 mod 32 = 4 -> rows 4 banks apart

// ---------------------------------------------------------------------------
// k_gates: fused {argmax-reduce -> token, embed gather, LSTM gates GEMM, cell}.
//   grid = 512 blocks: jt = blockIdx>>4 (32 tiles of 16 j), bt = blockIdx&15
//   (16 tiles of 4 b).  2 blocks/CU -> 2 waves/SIMD (was 1 at grid=256).
//   Prologue: this block's 4 tokens (step==0: caps; else reduce the 500
//   argmax partials, 64 lanes per b, first-index tie-break == jnp.argmax).
//   Staging: x = embW[tok[b]] and h (4 rows x 512 f, stride XPAD) in LDS.
//   Main: thread (j_l 0..15, kq 0..3, b_l 0..3): 4 gate quarter-dots of
//   length 256 over the combined [x;h] 1024-vector (kq 0,1 -> x.Wih halves,
//   kq 2,3 -> h.Whh halves); in-wave reduce via shfl_xor(4), shfl_xor(8).
//   Epilogue (kq==0 lanes): biases + cell, write h (b-major), hT (k-major
//   for k_logits' uniform reads), c.
// ---------------------------------------------------------------------------
__global__ __launch_bounds__(256) void k_gates(
    const float* __restrict__ embW, const float* __restrict__ Wih,
    const float* __restrict__ Whh, const float* __restrict__ bih,
    const float* __restrict__ bhh, const float* __restrict__ hin,
    float* __restrict__ hout, const float* __restrict__ cin,
    float* __restrict__ cout, float* __restrict__ hT,
    const int* __restrict__ caps,
    const float* __restrict__ pval, const int* __restrict__ pidx,
    int step)
{
    __shared__ float xs[4 * XPAD];
    __shared__ float hs[4 * XPAD];
    __shared__ int   tok_s[4];

    const int jt = blockIdx.x >> 4;      // 0..31
    const int bt = blockIdx.x & 15;      // 0..15
    const int t  = threadIdx.x;

    // ---- tokens for this block's 4 b's ----
    if (step == 0) {
        if (t < 4) tok_s[t] = caps[bt * 4 + t];
    } else {
        const int b_l2 = t >> 6;         // 0..3 (one wave per b)
        const int part = t & 63;
        const int b2   = bt * 4 + b_l2;
        float best = -3.4e38f; int bi = 0x7fffffff;
        #pragma unroll 4
        for (int i = part; i < NLOGB; i += 64) {
            float v = pval[b2 * PSTRIDE + i];
            int  ix = pidx[b2 * PSTRIDE + i];
            if (v > best || (v == best && ix < bi)) { best = v; bi = ix; }
        }
        #pragma unroll
        for (int off = 1; off < 64; off <<= 1) {
            float ov = __shfl_xor(best, off);
            int   oi = __shfl_xor(bi, off);
            if (ov > best || (ov == best && oi < bi)) { best = ov; bi = oi; }
        }
        if (part == 0) tok_s[b_l2] = bi;
    }
    __syncthreads();

    // ---- stage x and h: 4 rows x 512 floats each; 64 threads per row ----
    {
        const int rr = t >> 6;           // 0..3 (b_local)
        const int cc = t & 63;
        const int b  = bt * 4 + rr;
        const int tk = tok_s[rr];
        const float4* xrow = (const float4*)(embW + (size_t)tk * EE);
        const float4* hrow = (const float4*)(hin + (size_t)b * HH);
        float4* xd = (float4*)(xs + rr * XPAD);   // rr*516*4 B is 16B-aligned
        float4* hd = (float4*)(hs + rr * XPAD);
        #pragma unroll
        for (int i = 0; i < 2; ++i) {
            xd[cc + i * 64] = xrow[cc + i * 64];
            hd[cc + i * 64] = hrow[cc + i * 64];
        }
    }
    __syncthreads();

    const int b_l = t & 3;               // 0..3
    const int kq  = (t >> 2) & 3;        // 0..3: quarter of combined [x;h]
    const int j_l = t >> 4;              // 0..15
    const int j   = jt * 16 + j_l;
    const int b   = bt * 4 + b_l;

    const float*  Wsrc = (kq < 2) ? Wih : Whh;
    const float4* vsrc = (const float4*)(((kq < 2) ? xs : hs)
                                         + b_l * XPAD + (kq & 1) * 256);
    const int     wofs = (kq & 1) * 64;  // float4 offset into the 512-row

    float g4[4];
    #pragma unroll
    for (int g = 0; g < 4; ++g) {
        const float4* wr = (const float4*)(Wsrc + (size_t)(g * HH + j) * EE)
                           + wofs;
        float s = 0.f;
        #pragma unroll 8
        for (int q = 0; q < 64; ++q) {
            float4 w = wr[q];
            float4 v = vsrc[q];
            s = fmaf(w.x, v.x, s); s = fmaf(w.y, v.y, s);
            s = fmaf(w.z, v.z, s); s = fmaf(w.w, v.w, s);
        }
        g4[g] = s;
    }
    #pragma unroll
    for (int g = 0; g < 4; ++g) {
        g4[g] += __shfl_xor(g4[g], 4);
        g4[g] += __shfl_xor(g4[g], 8);
    }

    if (kq == 0) {
        float gi = g4[0] + bih[j]          + bhh[j];
        float gf = g4[1] + bih[HH + j]     + bhh[HH + j];
        float gg = g4[2] + bih[2*HH + j]   + bhh[2*HH + j];
        float go = g4[3] + bih[3*HH + j]   + bhh[3*HH + j];
        float si = 1.f / (1.f + expf(-gi));
        float sf = 1.f / (1.f + expf(-gf));
        float sg = tanhf(gg);
        float so = 1.f / (1.f + expf(-go));
        const int ci = b * HH + j;
        float cn = sf * cin[ci] + si * sg;
        float hn = so * tanhf(cn);
        cout[ci] = cn;
        hout[ci] = hn;
        hT[(size_t)j * BB + b] = hn;
    }
}

// ---------------------------------------------------------------------------
// k_logits: out[b][n] = h[b] . lin_W[n] + lin_b[n].  grid = 500 x 256.
//   Thread = (col 0..63 -> n, wave 0..3 -> 16-batch group). Each thread:
//   16 fp32 accumulators (ALL loops touching acc are fully unrolled ->
//   compile-time indices -> registers, no scratch), full K=512 per thread.
//   lin_W: one float4/lane/k4 (each row read by the block's 4 waves, L1-hit).
//   hT[k][b]: wave-uniform addresses (b0 via readfirstlane -> s_load),
//   no LDS, no cross-wave reduce.
//   Epilogue per b (unrolled): bias, coalesced dout write, 64-lane shfl
//   argmax (first-index tie-break), partials to pval/pidx.
// ---------------------------------------------------------------------------
__global__ __launch_bounds__(256) void k_logits(
    const float* __restrict__ linW, const float* __restrict__ linb,
    const float* __restrict__ hT, float* __restrict__ dout,
    float* __restrict__ pval, int* __restrict__ pidx, int step)
{
    const int col = threadIdx.x & 63;
    const int b0  = __builtin_amdgcn_readfirstlane((threadIdx.x >> 6) << 4);
    const int n   = blockIdx.x * 64 + col;

    const float4* wrow = (const float4*)(linW + (size_t)n * HH);
    const float*  hb   = hT + b0;        // hT[k][b], k-major stride BB

    float acc[16];
    #pragma unroll
    for (int i = 0; i < 16; ++i) acc[i] = 0.f;

    #pragma unroll 8
    for (int k4 = 0; k4 < 128; ++k4) {   // 4 k's per iteration
        const float4 w = wrow[k4];
        const float4* h0 = (const float4*)(hb + (size_t)(k4 * 4 + 0) * BB);
        const float4* h1 = (const float4*)(hb + (size_t)(k4 * 4 + 1) * BB);
        const float4* h2 = (const float4*)(hb + (size_t)(k4 * 4 + 2) * BB);
        const float4* h3 = (const float4*)(hb + (size_t)(k4 * 4 + 3) * BB);
        #pragma unroll
        for (int j = 0; j < 4; ++j) {
            float4 hv;
            hv = h0[j];
            acc[j*4+0] = fmaf(w.x, hv.x, acc[j*4+0]);
            acc[j*4+1] = fmaf(w.x, hv.y, acc[j*4+1]);
            acc[j*4+2] = fmaf(w.x, hv.z, acc[j*4+2]);
            acc[j*4+3] = fmaf(w.x, hv.w, acc[j*4+3]);
            hv = h1[j];
            acc[j*4+0] = fmaf(w.y, hv.x, acc[j*4+0]);
            acc[j*4+1] = fmaf(w.y, hv.y, acc[j*4+1]);
            acc[j*4+2] = fmaf(w.y, hv.z, acc[j*4+2]);
            acc[j*4+3] = fmaf(w.y, hv.w, acc[j*4+3]);
            hv = h2[j];
            acc[j*4+0] = fmaf(w.z, hv.x, acc[j*4+0]);
            acc[j*4+1] = fmaf(w.z, hv.y, acc[j*4+1]);
            acc[j*4+2] = fmaf(w.z, hv.z, acc[j*4+2]);
            acc[j*4+3] = fmaf(w.z, hv.w, acc[j*4+3]);
            hv = h3[j];
            acc[j*4+0] = fmaf(w.w, hv.x, acc[j*4+0]);
            acc[j*4+1] = fmaf(w.w, hv.y, acc[j*4+1]);
            acc[j*4+2] = fmaf(w.w, hv.z, acc[j*4+2]);
            acc[j*4+3] = fmaf(w.w, hv.w, acc[j*4+3]);
        }
    }

    const float bias = linb[n];
    #pragma unroll
    for (int i = 0; i < 16; ++i) {
        const int b = b0 + i;
        float v = acc[i] + bias;
        dout[((size_t)(b * TT + step)) * VV + n] = v;
        float mv = v; int mi = n;
        #pragma unroll
        for (int off = 32; off > 0; off >>= 1) {
            float ov = __shfl_xor(mv, off);
            int   oi = __shfl_xor(mi, off);
            if (ov > mv || (ov == mv && oi < mi)) { mv = ov; mi = oi; }
        }
        if (col == 0) {
            pval[b * PSTRIDE + blockIdx.x] = mv;
            pidx[b * PSTRIDE + blockIdx.x] = mi;
        }
    }
}

// ---------------------------------------------------------------------------
extern "C" void kernel_launch(void* const* d_in, const int* in_sizes, int n_in,
                              void* d_out, int out_size, void* d_ws, size_t ws_size,
                              hipStream_t stream)
{
    const float* feat = (const float*)d_in[0];   // (B,H)
    const int*   caps = (const int*)d_in[1];     // (B,1) int32
    // d_in[2] = lengths (=32), unused
    const float* embW = (const float*)d_in[3];   // (V,E)
    const float* Wih  = (const float*)d_in[4];   // (4H,E)
    const float* Whh  = (const float*)d_in[5];   // (4H,H)
    const float* bih  = (const float*)d_in[6];   // (4H,)
    const float* bhh  = (const float*)d_in[7];   // (4H,)
    const float* linW = (const float*)d_in[8];   // (V,H)
    const float* linb = (const float*)d_in[9];   // (V,)
    float* dout = (float*)d_out;                 // (B,T,V) f32

    // workspace layout (~0.9 MiB)
    float* ws_f = (float*)d_ws;
    float* ha   = ws_f;                      // 32768 f
    float* hb   = ha + BB * HH;              // 32768 f
    float* cb   = hb + BB * HH;              // 32768 f
    float* hT   = cb + BB * HH;              // 32768 f
    float* pval = hT + BB * HH;              // 64*512 f
    int*   pidx = (int*)(pval + BB * PSTRIDE);   // 64*512 i
    // no init kernel: step 0 reads feat (h,c) and caps (tok) directly

    for (int t = 0; t < TT; ++t) {
        const float* hin = (t == 0) ? feat : ((t & 1) ? ha : hb);
        float*      hout = (t & 1) ? hb : ha;
        const float* ci  = (t == 0) ? feat : cb;
        k_gates<<<512, 256, 0, stream>>>(embW, Wih, Whh, bih, bhh,
                                         hin, hout, ci, cb, hT,
                                         caps, pval, pidx, t);
        k_logits<<<NLOGB, 256, 0, stream>>>(linW, linb, hT, dout,
                                            pval, pidx, t);
    }
}